// Round 11
// baseline (331.466 us; speedup 1.0000x reference)
//
#include <hip/hip_runtime.h>
#include <math.h>

// CRF forward-score scan, faithful to the reference's quirky log_sum_exp.
// Base-2 factorization (HW-verified r5/r6/r8/r9/r10, absmax 0.0):
//   M2_i   = max_j(fv2_j + tr2_ij)
//   h_j    = exp2(fv2_j - M2_j - feat2_j)
//   fv2'_i = M2_i + 2*feat2_i + log2(sum_j exp2(tr2_ij) * h_j)
//
// Measured ladder (cyc/block-step): r5 3-wave+2bar 832 | r8 1-wave quad 975
// | r10 lane-per-row LDS-gather 1026 (VGPR=80 < 96 persistent => compiler
// spilled tr rows to scratch; also ~24 b128 broadcast reads = ~290 DS-pipe
// cyc/step). Model update: LDS RT ~200cyc, DS pipe ~12cyc/b128 serial.
//
// THIS ROUND: keep lane-per-row but do both 48-float all-gathers with
// v_readlane_b32 instead of LDS: 48x(readlane+add) for fv, 48x(readlane+
// fmac) for h. VALU-only transport: no DS ops in the loop except one
// prefetchable feat read, no barriers, no waitcnt, no latency heads.
// ~256 VALU instr/step ~= 570 cyc -> predict 115-140 us.
// Spill fix: amdgpu_waves_per_eu(1,1) pins 1 wave/EU -> full VGPR budget,
// keeps tr2r[48]+Er[48] resident (r10's failure mode).

#define TT 48
#define BB 128
#define SS 512
#define STARTI 46
#define ENDI 47
#define MINV 0.0001f
#define CHUNK 32
#define NCHUNK (SS / CHUNK)   // 16
#define GPT 6                 // gload16 per chunk: 32*48*4B / (64*16B)
#define LOG2E 1.44269504088896340736f
#define LN2   0.69314718055994530942f

#if __has_builtin(__builtin_amdgcn_exp2f)
#define EXP2F(x) __builtin_amdgcn_exp2f(x)
#else
#define EXP2F(x) exp2f(x)
#endif
#if __has_builtin(__builtin_amdgcn_logf)   // v_log_f32: log base 2
#define LOG2F(x) __builtin_amdgcn_logf(x)
#else
#define LOG2F(x) log2f(x)
#endif

// Broadcast lane k's value to all lanes via v_readlane (VALU, no memory).
#if __has_builtin(__builtin_amdgcn_readlane)
__device__ __forceinline__ float rdlane(float v, int k) {
    return __int_as_float(__builtin_amdgcn_readlane(__float_as_int(v), k));
}
#else
__device__ __forceinline__ float rdlane(float v, int k) {
    return __shfl(v, k, 64);
}
#endif

#if __has_builtin(__builtin_amdgcn_global_load_lds)
#define HAVE_GLOAD 1
__device__ __forceinline__ void gload16(const float* g, float* l) {
    __builtin_amdgcn_global_load_lds(
        (const __attribute__((address_space(1))) void*)g,
        (__attribute__((address_space(3))) void*)l, 16, 0, 0);
}
#else
#define HAVE_GLOAD 0
#endif

__device__ __forceinline__ float m3(float a, float b, float c) {
    return fmaxf(fmaxf(a, b), c);   // clang fuses to v_max3_f32
}

__global__ __launch_bounds__(64, 1)
__attribute__((amdgpu_waves_per_eu(1, 1)))
void crf_forward_kernel(
    const float* __restrict__ feats,   // [B, S, T]
    const float* __restrict__ trans,   // [T, T]
    float* __restrict__ out)           // [B]
{
    const int lane = threadIdx.x;                   // 0..63
    const int row  = (lane < TT) ? lane : TT - 1;   // lanes 48-63 shadow row 47
    const int b    = blockIdx.x;

    __shared__ __align__(16) float featbuf[2][CHUNK * TT];   // 2 x 6 KB

    // Own row of trans (base-2) and its exp2 -- persistent VGPRs.
    float tr2r[TT], Er[TT];
#pragma unroll
    for (int q = 0; q < 12; ++q) {
        float4 v = *reinterpret_cast<const float4*>(trans + row * TT + 4 * q);
        tr2r[4 * q + 0] = v.x * LOG2E; tr2r[4 * q + 1] = v.y * LOG2E;
        tr2r[4 * q + 2] = v.z * LOG2E; tr2r[4 * q + 3] = v.w * LOG2E;
    }
#pragma unroll
    for (int k = 0; k < TT; ++k) Er[k] = EXP2F(tr2r[k]);   // == exp(tr)

    const float teR = trans[ENDI * TT + row];   // terminal row, preloaded

    const float* fb = feats + (size_t)b * SS * TT;

    // Preload chunk 0.
#if HAVE_GLOAD
#pragma unroll
    for (int k = 0; k < GPT; ++k)
        gload16(fb + k * 256 + lane * 4, &featbuf[0][k * 256]);
#else
#pragma unroll
    for (int k = 0; k < GPT; ++k)
        *reinterpret_cast<float4*>(&featbuf[0][k * 256 + lane * 4]) =
            *reinterpret_cast<const float4*>(fb + k * 256 + lane * 4);
#endif

    // fv2_0: MIN*log2e everywhere except 0 at START (own row's value).
    float fvr = (row == STARTI) ? 0.0f : (MINV * LOG2E);

#if HAVE_GLOAD
    asm volatile("s_waitcnt vmcnt(0)" ::: "memory");
#endif

    for (int c = 0; c < NCHUNK; ++c) {
        const int buf = c & 1;
        const bool hp = (c + 1 < NCHUNK);
        if (hp) {
#if HAVE_GLOAD
#pragma unroll
            for (int k = 0; k < GPT; ++k)
                gload16(fb + (c + 1) * (CHUNK * TT) + k * 256 + lane * 4,
                        &featbuf[buf ^ 1][k * 256]);
#else
#pragma unroll
            for (int k = 0; k < GPT; ++k)
                *reinterpret_cast<float4*>(&featbuf[buf ^ 1][k * 256 + lane * 4]) =
                    *reinterpret_cast<const float4*>(
                        fb + (c + 1) * (CHUNK * TT) + k * 256 + lane * 4);
#endif
        }

#pragma unroll 1
        for (int sl = 0; sl < CHUNK; ++sl) {
            // Own feat (stride-1 lanes, 2-way bank alias = free; only DS op).
            const float feat2 = featbuf[buf][sl * TT + row] * LOG2E;

            // ---- pass 1: gather fv via readlane, local add + max tree ----
            float pm[12];
#pragma unroll
            for (int g = 0; g < 12; ++g) {
                const float a0 = rdlane(fvr, 4 * g + 0) + tr2r[4 * g + 0];
                const float a1 = rdlane(fvr, 4 * g + 1) + tr2r[4 * g + 1];
                const float a2 = rdlane(fvr, 4 * g + 2) + tr2r[4 * g + 2];
                const float a3 = rdlane(fvr, 4 * g + 3) + tr2r[4 * g + 3];
                pm[g] = fmaxf(fmaxf(a0, a1), fmaxf(a2, a3));
            }
            const float q0 = m3(pm[0], pm[1],  pm[2]);
            const float q1 = m3(pm[3], pm[4],  pm[5]);
            const float q2 = m3(pm[6], pm[7],  pm[8]);
            const float q3 = m3(pm[9], pm[10], pm[11]);
            const float M2 = fmaxf(fmaxf(q0, q1), fmaxf(q2, q3));

            const float h   = EXP2F((fvr - feat2) - M2);
            const float qv2 = M2 + 2.0f * feat2;

            // ---- pass 2: gather h via readlane, fmac with Er ----
            float acc0 = 0.0f, acc1 = 0.0f, acc2 = 0.0f, acc3 = 0.0f;
#pragma unroll
            for (int g = 0; g < 12; ++g) {
                acc0 = fmaf(Er[4 * g + 0], rdlane(h, 4 * g + 0), acc0);
                acc1 = fmaf(Er[4 * g + 1], rdlane(h, 4 * g + 1), acc1);
                acc2 = fmaf(Er[4 * g + 2], rdlane(h, 4 * g + 2), acc2);
                acc3 = fmaf(Er[4 * g + 3], rdlane(h, 4 * g + 3), acc3);
            }
            const float dot = (acc0 + acc1) + (acc2 + acc3);

            fvr = qv2 + LOG2F(dot);

#if HAVE_GLOAD
            if (sl == CHUNK - 2 && hp)
                asm volatile("s_waitcnt vmcnt(0)" ::: "memory");
#endif
        }
    }

    // ---- terminal: out[b] = LSE_j( fv_j + trans[END][j] ) ----
    // Lanes 48-63 duplicate row 47: harmless for max, zeroed for the sum.
    {
        const float sc = fmaf(fvr, LN2, teR);
        float m = sc;
#pragma unroll
        for (int off = 32; off >= 1; off >>= 1)
            m = fmaxf(m, __shfl_xor(m, off));
        float e = (lane < TT) ? __expf(sc - m) : 0.0f;
#pragma unroll
        for (int off = 32; off >= 1; off >>= 1)
            e += __shfl_xor(e, off);
        if (lane == 0) out[b] = m + __logf(e);
    }
}

extern "C" void kernel_launch(void* const* d_in, const int* in_sizes, int n_in,
                              void* d_out, int out_size, void* d_ws, size_t ws_size,
                              hipStream_t stream) {
    (void)in_sizes; (void)n_in; (void)out_size; (void)d_ws; (void)ws_size;
    const float* feats = (const float*)d_in[0];   // [128, 512, 48] f32
    const float* trans = (const float*)d_in[1];   // [48, 48] f32
    float* out = (float*)d_out;                   // [128] f32
    crf_forward_kernel<<<dim3(BB), dim3(64), 0, stream>>>(feats, trans, out);
}